// Round 1
// baseline (48.788 us; speedup 1.0000x reference)
//
#include <hip/hip_runtime.h>
#include <math.h>

// Problem constants (from reference): B=2048, N=16384, D=16
#define BB 2048
#define NN 16384
#define DD 16
#define KSLICES 128              // n-slices for parallelism: 32 bg * 128 = 4096 waves
#define SLICE_N (NN / KSLICES)   // 128 kernels per wave
#define NBG (BB / 64)            // 32 b-groups of 64 samples (one per lane)

__device__ __forceinline__ float exp2_fast(float v) {
    return __builtin_amdgcn_exp2f(v);
}

// ---------------------------------------------------------------------------
// Prep: per-kernel constants. mu2[n][d] = 2*mu[n][d];
// params[n] = (A2, B2) with  e2(b,n) = A2*(xsq_b - 2*x.mu_n) + B2  (base-2)
//   A2 = -0.5*log2e / sigma^2
//   B2 = A2*||mu||^2 - log2e*(D*sigmatilde + 0.5*D*log(2pi)) + log2(w)
// ---------------------------------------------------------------------------
__global__ __launch_bounds__(256) void kde_prep(
    const float* __restrict__ mu, const float* __restrict__ sigmatilde,
    const float* __restrict__ weights, float* __restrict__ mu2,
    float2* __restrict__ params)
{
    int n = blockIdx.x * 256 + threadIdx.x;
    if (n >= NN) return;
    const float4* m4 = (const float4*)(mu + (size_t)n * DD);
    float4 a = m4[0], b = m4[1], c = m4[2], d = m4[3];
    float musq = a.x*a.x + a.y*a.y + a.z*a.z + a.w*a.w
               + b.x*b.x + b.y*b.y + b.z*b.z + b.w*b.w
               + c.x*c.x + c.y*c.y + c.z*c.z + c.w*c.w
               + d.x*d.x + d.y*d.y + d.z*d.z + d.w*d.w;
    float4* o4 = (float4*)(mu2 + (size_t)n * DD);
    o4[0] = make_float4(2.f*a.x, 2.f*a.y, 2.f*a.z, 2.f*a.w);
    o4[1] = make_float4(2.f*b.x, 2.f*b.y, 2.f*b.z, 2.f*b.w);
    o4[2] = make_float4(2.f*c.x, 2.f*c.y, 2.f*c.z, 2.f*c.w);
    o4[3] = make_float4(2.f*d.x, 2.f*d.y, 2.f*d.z, 2.f*d.w);

    float st = sigmatilde[n];
    float w  = weights[n];
    float sigma = expf(st);
    const float LOG2E  = 1.4426950408889634f;
    const float LOG2PI = 1.8378770664093453f;   // ln(2*pi)
    float A2 = -0.5f * LOG2E / (sigma * sigma);
    float B2 = A2 * musq - LOG2E * ((float)DD * st + 0.5f * (float)DD * LOG2PI)
             + log2f(w);
    params[n] = make_float2(A2, B2);
}

// ---------------------------------------------------------------------------
// Main: lane <-> sample b (x row in 16 VGPRs), n-loop wave-uniform so mu2 and
// params come in via scalar loads (SGPR broadcast). Online base-2 LSE per lane.
// Partial (m, s) per (slice, b) written coalesced: partials[slice*B + b].
// ---------------------------------------------------------------------------
__global__ __launch_bounds__(256) void kde_main(
    const float* __restrict__ x, const float* __restrict__ mu2,
    const float2* __restrict__ params, float2* __restrict__ partials)
{
    int lane = threadIdx.x & 63;
    // force wave-uniformity so the compiler proves scalar loads
    int wave = __builtin_amdgcn_readfirstlane((int)(threadIdx.x >> 6));
    int bg = blockIdx.x % NBG;
    int sg = blockIdx.x / NBG;
    int slice = sg * 4 + wave;
    int b = bg * 64 + lane;

    const float4* xr = (const float4*)(x + (size_t)b * DD);
    float4 x0 = xr[0], x1 = xr[1], x2 = xr[2], x3 = xr[3];
    float xsq = x0.x*x0.x + x0.y*x0.y + x0.z*x0.z + x0.w*x0.w
              + x1.x*x1.x + x1.y*x1.y + x1.z*x1.z + x1.w*x1.w
              + x2.x*x2.x + x2.y*x2.y + x2.z*x2.z + x2.w*x2.w
              + x3.x*x3.x + x3.y*x3.y + x3.z*x3.z + x3.w*x3.w;

    int n0 = slice * SLICE_N;
    const float*  mp = mu2 + (size_t)n0 * DD;
    const float2* pp = params + n0;

    float m = -INFINITY;
    float s = 0.0f;

    #pragma unroll 2
    for (int i = 0; i < SLICE_N; ++i) {
        const float* mn = mp + i * DD;   // uniform address -> s_load_dwordx16
        // dot(x, 2*mu_n) with 4 independent accumulator chains
        float d0 = x0.x * mn[0];
        float d1 = x0.y * mn[1];
        float d2 = x0.z * mn[2];
        float d3 = x0.w * mn[3];
        d0 = fmaf(x1.x, mn[4],  d0);
        d1 = fmaf(x1.y, mn[5],  d1);
        d2 = fmaf(x1.z, mn[6],  d2);
        d3 = fmaf(x1.w, mn[7],  d3);
        d0 = fmaf(x2.x, mn[8],  d0);
        d1 = fmaf(x2.y, mn[9],  d1);
        d2 = fmaf(x2.z, mn[10], d2);
        d3 = fmaf(x2.w, mn[11], d3);
        d0 = fmaf(x3.x, mn[12], d0);
        d1 = fmaf(x3.y, mn[13], d1);
        d2 = fmaf(x3.z, mn[14], d2);
        d3 = fmaf(x3.w, mn[15], d3);
        float dd = (d0 + d1) + (d2 + d3);

        float2 P = pp[i];                 // uniform -> s_load_dwordx2
        float e = fmaf(P.x, xsq - dd, P.y);

        float m1 = fmaxf(m, e);
        s = fmaf(s, exp2_fast(m - m1), exp2_fast(e - m1));
        m = m1;
    }

    partials[(size_t)slice * BB + b] = make_float2(m, s);
}

// ---------------------------------------------------------------------------
// Reduce: one 64-lane wave per sample b; merge KSLICES partials, butterfly.
// out[b] = ln2 * (m + log2(s))
// ---------------------------------------------------------------------------
__global__ __launch_bounds__(64) void kde_reduce(
    const float2* __restrict__ partials, float* __restrict__ out)
{
    int b = blockIdx.x;
    int lane = threadIdx.x;

    float m = -INFINITY;
    float s = 0.0f;
    #pragma unroll
    for (int k = lane; k < KSLICES; k += 64) {
        float2 v = partials[(size_t)k * BB + b];
        float m1 = fmaxf(m, v.x);
        s = fmaf(s, exp2_fast(m - m1), v.y * exp2_fast(v.x - m1));
        m = m1;
    }
    #pragma unroll
    for (int off = 32; off > 0; off >>= 1) {
        float mo = __shfl_xor(m, off, 64);
        float so = __shfl_xor(s, off, 64);
        float m1 = fmaxf(m, mo);
        s = s * exp2_fast(m - m1) + so * exp2_fast(mo - m1);
        m = m1;
    }
    if (lane == 0) {
        out[b] = (m + log2f(s)) * 0.6931471805599453f;
    }
}

extern "C" void kernel_launch(void* const* d_in, const int* in_sizes, int n_in,
                              void* d_out, int out_size, void* d_ws, size_t ws_size,
                              hipStream_t stream) {
    const float* x  = (const float*)d_in[0];
    const float* mu = (const float*)d_in[1];
    const float* st = (const float*)d_in[2];
    const float* w  = (const float*)d_in[3];
    float* out = (float*)d_out;

    char* ws = (char*)d_ws;
    float*  mu2      = (float*)ws;                                  // N*D*4   = 1 MB
    float2* params   = (float2*)(ws + (size_t)NN * DD * 4);          // N*8     = 128 KB
    float2* partials = (float2*)(ws + (size_t)NN * DD * 4 + (size_t)NN * 8); // B*K*8 = 2 MB

    hipLaunchKernelGGL(kde_prep, dim3(NN / 256), dim3(256), 0, stream,
                       mu, st, w, mu2, params);
    hipLaunchKernelGGL(kde_main, dim3(NBG * (KSLICES / 4)), dim3(256), 0, stream,
                       x, mu2, params, partials);
    hipLaunchKernelGGL(kde_reduce, dim3(BB), dim3(64), 0, stream,
                       partials, out);
}

// Round 2
// 30.795 us; speedup vs baseline: 1.5843x; 1.5843x over previous
//
#include <hip/hip_runtime.h>
#include <math.h>

// B=2048, N=16384, D=16
#define BB 2048
#define NN 16384
#define KAUG 32                 // augmented K (18 used, padded to MFMA K=32)
#define NSLICES 128             // n-slices; waves = 32 bquads * 128 = 4096
#define CHUNKS 8                // 16-n chunks per slice (128 n per slice)
#define LN2 0.6931471805599453f
#define LOG2E 1.4426950408889634f
#define LN2PI 1.8378770664093453f

typedef __attribute__((ext_vector_type(8))) short bf16x8;
typedef __attribute__((ext_vector_type(4))) float f32x4;

__device__ __forceinline__ float EXP2(float v) { return __builtin_amdgcn_exp2f(v); }

__device__ __forceinline__ ushort f2bf(float f) {
    unsigned u = __float_as_uint(f);
    unsigned r = (u + 0x7FFFu + ((u >> 16) & 1u)) >> 16;   // RNE
    return (ushort)r;
}
__device__ __forceinline__ float bf2f(ushort h) {
    return __uint_as_float(((unsigned)h) << 16);
}

// ---------------------------------------------------------------------------
// Prep (one kernel, two paths):
//  mu-path: A_aug rows [N][32]: a[k]=A2*(-2mu[k]) k<16; a[16]=A2*musq+C2;
//           a[17]=A2; pad 0.  A2=-0.5*log2e/sigma^2,
//           C2=-log2e*(D*st+0.5*D*ln2pi)+log2(w).  Split hi/lo bf16.
//  x-path:  X_aug rows [B][32]: x[k] k<16; 1; xsq; pad 0. Split hi/lo bf16.
// ---------------------------------------------------------------------------
__global__ __launch_bounds__(256) void kde_prep(
    const float* __restrict__ x, const float* __restrict__ mu,
    const float* __restrict__ sigmatilde, const float* __restrict__ weights,
    ushort* __restrict__ Ah, ushort* __restrict__ Al,
    ushort* __restrict__ Xh, ushort* __restrict__ Xl)
{
    float v[KAUG];
    ushort *dh, *dl;
    if (blockIdx.x < 64) {
        int n = blockIdx.x * 256 + threadIdx.x;
        const float4* m4 = (const float4*)(mu + (size_t)n * 16);
        float4 a = m4[0], b = m4[1], c = m4[2], d = m4[3];
        float musq = a.x*a.x + a.y*a.y + a.z*a.z + a.w*a.w
                   + b.x*b.x + b.y*b.y + b.z*b.z + b.w*b.w
                   + c.x*c.x + c.y*c.y + c.z*c.z + c.w*c.w
                   + d.x*d.x + d.y*d.y + d.z*d.z + d.w*d.w;
        float st = sigmatilde[n], w = weights[n];
        float sigma = expf(st);
        float A2 = -0.5f * LOG2E / (sigma * sigma);
        float C2 = -LOG2E * (16.f * st + 8.f * LN2PI) + log2f(w);
        const float* mn = mu + (size_t)n * 16;
        #pragma unroll
        for (int k = 0; k < 16; ++k) v[k] = A2 * (-2.f * mn[k]);
        v[16] = fmaf(A2, musq, C2);
        v[17] = A2;
        #pragma unroll
        for (int k = 18; k < KAUG; ++k) v[k] = 0.f;
        dh = Ah + (size_t)n * KAUG;
        dl = Al + (size_t)n * KAUG;
    } else {
        int b = (blockIdx.x - 64) * 256 + threadIdx.x;
        const float4* x4 = (const float4*)(x + (size_t)b * 16);
        float4 a = x4[0], bb = x4[1], c = x4[2], d = x4[3];
        float xsq = a.x*a.x + a.y*a.y + a.z*a.z + a.w*a.w
                  + bb.x*bb.x + bb.y*bb.y + bb.z*bb.z + bb.w*bb.w
                  + c.x*c.x + c.y*c.y + c.z*c.z + c.w*c.w
                  + d.x*d.x + d.y*d.y + d.z*d.z + d.w*d.w;
        const float* xr = x + (size_t)b * 16;
        #pragma unroll
        for (int k = 0; k < 16; ++k) v[k] = xr[k];
        v[16] = 1.0f;
        v[17] = xsq;
        #pragma unroll
        for (int k = 18; k < KAUG; ++k) v[k] = 0.f;
        dh = Xh + (size_t)b * KAUG;
        dl = Xl + (size_t)b * KAUG;
    }
    unsigned uh[KAUG / 2], ul[KAUG / 2];
    #pragma unroll
    for (int k = 0; k < KAUG / 2; ++k) {
        ushort h0 = f2bf(v[2*k]),   h1 = f2bf(v[2*k+1]);
        ushort l0 = f2bf(v[2*k]   - bf2f(h0));
        ushort l1 = f2bf(v[2*k+1] - bf2f(h1));
        uh[k] = (unsigned)h0 | ((unsigned)h1 << 16);
        ul[k] = (unsigned)l0 | ((unsigned)l1 << 16);
    }
    uint4* ph = (uint4*)dh;
    uint4* pl = (uint4*)dl;
    #pragma unroll
    for (int k = 0; k < KAUG / 8; ++k) {
        ph[k] = make_uint4(uh[4*k], uh[4*k+1], uh[4*k+2], uh[4*k+3]);
        pl[k] = make_uint4(ul[4*k], ul[4*k+1], ul[4*k+2], ul[4*k+3]);
    }
}

// ---------------------------------------------------------------------------
// Main: wave owns 4 b-tiles (64 samples) x one n-slice (128 kernels).
// Per 16-n chunk: 3 MFMAs (split-bf16) give acc = e2 (base-2 exponent)
// directly; lane's 4 acc regs = 4 n's for col b = lane&15. Online LSE per
// lane; exact wave-uniform skip when chunk cannot contribute (underflow).
// ---------------------------------------------------------------------------
__global__ __launch_bounds__(256) void kde_main(
    const ushort* __restrict__ Ah, const ushort* __restrict__ Al,
    const ushort* __restrict__ Xh, const ushort* __restrict__ Xl,
    float2* __restrict__ part)
{
    int lane = threadIdx.x & 63;
    int w = blockIdx.x * 4 + (threadIdx.x >> 6);
    int slice = w >> 5;          // 0..127  (waves in a block share the slice)
    int bquad = w & 31;          // 0..31   (64 samples)
    int l15 = lane & 15, g = lane >> 4;

    bf16x8 bh[4], bl[4];
    #pragma unroll
    for (int bt = 0; bt < 4; ++bt) {
        size_t off = (size_t)(bquad * 64 + bt * 16 + l15) * KAUG + g * 8;
        bh[bt] = *(const bf16x8*)(Xh + off);
        bl[bt] = *(const bf16x8*)(Xl + off);
    }

    float m[4], s[4];
    #pragma unroll
    for (int bt = 0; bt < 4; ++bt) { m[bt] = -INFINITY; s[bt] = 0.f; }

    int n0 = slice * (16 * CHUNKS);
    #pragma unroll 2
    for (int c = 0; c < CHUNKS; ++c) {
        size_t roff = (size_t)(n0 + c * 16 + l15) * KAUG + g * 8;
        bf16x8 ah = *(const bf16x8*)(Ah + roff);
        bf16x8 al = *(const bf16x8*)(Al + roff);
        #pragma unroll
        for (int bt = 0; bt < 4; ++bt) {
            f32x4 acc = {0.f, 0.f, 0.f, 0.f};
            acc = __builtin_amdgcn_mfma_f32_16x16x32_bf16(al, bh[bt], acc, 0, 0, 0);
            acc = __builtin_amdgcn_mfma_f32_16x16x32_bf16(ah, bl[bt], acc, 0, 0, 0);
            acc = __builtin_amdgcn_mfma_f32_16x16x32_bf16(ah, bh[bt], acc, 0, 0, 0);
            float cmax = fmaxf(fmaxf(acc[0], acc[1]), fmaxf(acc[2], acc[3]));
            // exact skip: if every lane's chunk-max underflows vs running max,
            // all exp2() would return +0.0f and m would not change.
            if (__any(cmax >= m[bt] - 126.f)) {
                float mn = fmaxf(m[bt], cmax);
                float t = EXP2(acc[0] - mn) + EXP2(acc[1] - mn)
                        + EXP2(acc[2] - mn) + EXP2(acc[3] - mn);
                s[bt] = fmaf(s[bt], EXP2(m[bt] - mn), t);
                m[bt] = mn;
            }
        }
    }

    // merge the 4 lane-groups (rows live in lanes l15, l15+16, l15+32, l15+48)
    #pragma unroll
    for (int bt = 0; bt < 4; ++bt) {
        float mm = m[bt], ss = s[bt];
        #pragma unroll
        for (int off = 16; off <= 32; off <<= 1) {
            float mo = __shfl_xor(mm, off, 64);
            float so = __shfl_xor(ss, off, 64);
            float mn = fmaxf(mm, mo);
            ss = ss * EXP2(mm - mn) + so * EXP2(mo - mn);
            mm = mn;
        }
        if (lane < 16) {
            int b = bquad * 64 + bt * 16 + lane;
            part[(size_t)slice * BB + b] = make_float2(mm, ss);
        }
    }
}

// ---------------------------------------------------------------------------
// Reduce: one wave per sample; 128 slice-partials -> butterfly -> out.
// ---------------------------------------------------------------------------
__global__ __launch_bounds__(64) void kde_reduce(
    const float2* __restrict__ part, float* __restrict__ out)
{
    int b = blockIdx.x, t = threadIdx.x;
    float2 v0 = part[(size_t)t * BB + b];
    float2 v1 = part[(size_t)(t + 64) * BB + b];
    float mm = fmaxf(v0.x, v1.x);
    float ss = v0.y * EXP2(v0.x - mm) + v1.y * EXP2(v1.x - mm);
    #pragma unroll
    for (int off = 32; off; off >>= 1) {
        float mo = __shfl_xor(mm, off, 64);
        float so = __shfl_xor(ss, off, 64);
        float mn = fmaxf(mm, mo);
        ss = ss * EXP2(mm - mn) + so * EXP2(mo - mn);
        mm = mn;
    }
    if (t == 0) out[b] = (mm + __log2f(ss)) * LN2;
}

extern "C" void kernel_launch(void* const* d_in, const int* in_sizes, int n_in,
                              void* d_out, int out_size, void* d_ws, size_t ws_size,
                              hipStream_t stream) {
    const float* x  = (const float*)d_in[0];
    const float* mu = (const float*)d_in[1];
    const float* st = (const float*)d_in[2];
    const float* w  = (const float*)d_in[3];
    float* out = (float*)d_out;

    char* ws = (char*)d_ws;
    ushort* Ah = (ushort*)(ws);                       // 16384*32*2 = 1 MB
    ushort* Al = (ushort*)(ws + (1u << 20));          // 1 MB
    ushort* Xh = (ushort*)(ws + (2u << 20));          // 2048*32*2 = 128 KB
    ushort* Xl = (ushort*)(ws + (2u << 20) + (128u << 10));
    float2* part = (float2*)(ws + (4u << 20));        // 128*2048*8 = 2 MB

    hipLaunchKernelGGL(kde_prep, dim3(64 + 8), dim3(256), 0, stream,
                       x, mu, st, w, Ah, Al, Xh, Xl);
    hipLaunchKernelGGL(kde_main, dim3(32 * NSLICES / 4), dim3(256), 0, stream,
                       Ah, Al, Xh, Xl, part);
    hipLaunchKernelGGL(kde_reduce, dim3(BB), dim3(64), 0, stream,
                       part, out);
}

// Round 3
// 30.620 us; speedup vs baseline: 1.5933x; 1.0057x over previous
//
#include <hip/hip_runtime.h>
#include <math.h>

// B=2048, N=16384, D=16
#define BB 2048
#define NN 16384
#define KAUG 32                 // augmented K (18 used, padded to MFMA K=32)
#define NSLICES 128             // 128 n per slice, 8 chunks of 16
#define CHUNKS 8
#define BT 2                    // b-tiles per wave (32 samples)
#define NBG (BB / (16 * BT))    // 64 b-groups
#define LN2 0.6931471805599453f
#define LOG2E 1.4426950408889634f
#define LN2PI 1.8378770664093453f

typedef __attribute__((ext_vector_type(8))) short bf16x8;
typedef __attribute__((ext_vector_type(4))) float f32x4;

__device__ __forceinline__ float EXP2(float v) { return __builtin_amdgcn_exp2f(v); }

__device__ __forceinline__ ushort f2bf(float f) {
    unsigned u = __float_as_uint(f);
    unsigned r = (u + 0x7FFFu + ((u >> 16) & 1u)) >> 16;   // RNE
    return (ushort)r;
}
__device__ __forceinline__ float bf2f(ushort h) {
    return __uint_as_float(((unsigned)h) << 16);
}

// ---------------------------------------------------------------------------
// Prep: A_aug rows [N][32]: a[k]=A2*(-2mu[k]) k<16; a[16]=A2*musq+C2; a[17]=A2.
//       X_aug rows [B][32]: x[k] k<16; 1; xsq.  Both split hi/lo bf16 so that
//       acc = A_aug . X_aug = e2 (base-2 exponent) directly.
// ---------------------------------------------------------------------------
__global__ __launch_bounds__(256) void kde_prep(
    const float* __restrict__ x, const float* __restrict__ mu,
    const float* __restrict__ sigmatilde, const float* __restrict__ weights,
    ushort* __restrict__ Ah, ushort* __restrict__ Al,
    ushort* __restrict__ Xh, ushort* __restrict__ Xl)
{
    float v[KAUG];
    ushort *dh, *dl;
    if (blockIdx.x < 64) {
        int n = blockIdx.x * 256 + threadIdx.x;
        const float4* m4 = (const float4*)(mu + (size_t)n * 16);
        float4 a = m4[0], b = m4[1], c = m4[2], d = m4[3];
        float musq = a.x*a.x + a.y*a.y + a.z*a.z + a.w*a.w
                   + b.x*b.x + b.y*b.y + b.z*b.z + b.w*b.w
                   + c.x*c.x + c.y*c.y + c.z*c.z + c.w*c.w
                   + d.x*d.x + d.y*d.y + d.z*d.z + d.w*d.w;
        float st = sigmatilde[n], w = weights[n];
        float sigma = expf(st);
        float A2 = -0.5f * LOG2E / (sigma * sigma);
        float C2 = -LOG2E * (16.f * st + 8.f * LN2PI) + log2f(w);
        const float* mn = mu + (size_t)n * 16;
        #pragma unroll
        for (int k = 0; k < 16; ++k) v[k] = A2 * (-2.f * mn[k]);
        v[16] = fmaf(A2, musq, C2);
        v[17] = A2;
        #pragma unroll
        for (int k = 18; k < KAUG; ++k) v[k] = 0.f;
        dh = Ah + (size_t)n * KAUG;
        dl = Al + (size_t)n * KAUG;
    } else {
        int b = (blockIdx.x - 64) * 256 + threadIdx.x;
        const float4* x4 = (const float4*)(x + (size_t)b * 16);
        float4 a = x4[0], bb = x4[1], c = x4[2], d = x4[3];
        float xsq = a.x*a.x + a.y*a.y + a.z*a.z + a.w*a.w
                  + bb.x*bb.x + bb.y*bb.y + bb.z*bb.z + bb.w*bb.w
                  + c.x*c.x + c.y*c.y + c.z*c.z + c.w*c.w
                  + d.x*d.x + d.y*d.y + d.z*d.z + d.w*d.w;
        const float* xr = x + (size_t)b * 16;
        #pragma unroll
        for (int k = 0; k < 16; ++k) v[k] = xr[k];
        v[16] = 1.0f;
        v[17] = xsq;
        #pragma unroll
        for (int k = 18; k < KAUG; ++k) v[k] = 0.f;
        dh = Xh + (size_t)b * KAUG;
        dl = Xl + (size_t)b * KAUG;
    }
    unsigned uh[KAUG / 2], ul[KAUG / 2];
    #pragma unroll
    for (int k = 0; k < KAUG / 2; ++k) {
        ushort h0 = f2bf(v[2*k]),   h1 = f2bf(v[2*k+1]);
        ushort l0 = f2bf(v[2*k]   - bf2f(h0));
        ushort l1 = f2bf(v[2*k+1] - bf2f(h1));
        uh[k] = (unsigned)h0 | ((unsigned)h1 << 16);
        ul[k] = (unsigned)l0 | ((unsigned)l1 << 16);
    }
    uint4* ph = (uint4*)dh;
    uint4* pl = (uint4*)dl;
    #pragma unroll
    for (int k = 0; k < KAUG / 8; ++k) {
        ph[k] = make_uint4(uh[4*k], uh[4*k+1], uh[4*k+2], uh[4*k+3]);
        pl[k] = make_uint4(ul[4*k], ul[4*k+1], ul[4*k+2], ul[4*k+3]);
    }
}

// ---------------------------------------------------------------------------
// Main: wave owns 2 b-tiles (32 samples) x one n-slice (128 kernels).
// Branch-free online LSE; only cross-chunk dependency is one fmaf on s.
// 8192 waves -> target 6-8 waves/SIMD for latency hiding.
// ---------------------------------------------------------------------------
__global__ __launch_bounds__(256, 6) void kde_main(
    const ushort* __restrict__ Ah, const ushort* __restrict__ Al,
    const ushort* __restrict__ Xh, const ushort* __restrict__ Xl,
    float2* __restrict__ part)
{
    int lane = threadIdx.x & 63;
    int w = blockIdx.x * 4 + (threadIdx.x >> 6);
    int bg = w & (NBG - 1);      // 0..63
    int slice = w >> 6;          // 0..127
    int l15 = lane & 15, g = lane >> 4;

    bf16x8 bh[BT], bl[BT];
    #pragma unroll
    for (int bt = 0; bt < BT; ++bt) {
        size_t off = (size_t)(bg * (16 * BT) + bt * 16 + l15) * KAUG + g * 8;
        bh[bt] = *(const bf16x8*)(Xh + off);
        bl[bt] = *(const bf16x8*)(Xl + off);
    }

    float m[BT], s[BT];
    #pragma unroll
    for (int bt = 0; bt < BT; ++bt) { m[bt] = -INFINITY; s[bt] = 0.f; }

    int n0 = slice * (16 * CHUNKS);
    #pragma unroll 4
    for (int c = 0; c < CHUNKS; ++c) {
        size_t roff = (size_t)(n0 + c * 16 + l15) * KAUG + g * 8;
        bf16x8 ah = *(const bf16x8*)(Ah + roff);
        bf16x8 al = *(const bf16x8*)(Al + roff);
        #pragma unroll
        for (int bt = 0; bt < BT; ++bt) {
            f32x4 acc = {0.f, 0.f, 0.f, 0.f};
            acc = __builtin_amdgcn_mfma_f32_16x16x32_bf16(al, bh[bt], acc, 0, 0, 0);
            acc = __builtin_amdgcn_mfma_f32_16x16x32_bf16(ah, bl[bt], acc, 0, 0, 0);
            acc = __builtin_amdgcn_mfma_f32_16x16x32_bf16(ah, bh[bt], acc, 0, 0, 0);
            float cmax = fmaxf(fmaxf(acc[0], acc[1]), fmaxf(acc[2], acc[3]));
            float mn = fmaxf(m[bt], cmax);
            float e0 = EXP2(acc[0] - mn), e1 = EXP2(acc[1] - mn);
            float e2 = EXP2(acc[2] - mn), e3 = EXP2(acc[3] - mn);
            float r  = EXP2(m[bt] - mn);
            float t  = (e0 + e1) + (e2 + e3);
            s[bt] = fmaf(s[bt], r, t);
            m[bt] = mn;
        }
    }

    // merge the 4 lane-groups (rows n = g*4+reg live in lane groups g)
    #pragma unroll
    for (int bt = 0; bt < BT; ++bt) {
        float mm = m[bt], ss = s[bt];
        #pragma unroll
        for (int off = 16; off <= 32; off <<= 1) {
            float mo = __shfl_xor(mm, off, 64);
            float so = __shfl_xor(ss, off, 64);
            float mn = fmaxf(mm, mo);
            ss = ss * EXP2(mm - mn) + so * EXP2(mo - mn);
            mm = mn;
        }
        if (lane < 16) {
            int b = bg * (16 * BT) + bt * 16 + lane;
            part[(size_t)slice * BB + b] = make_float2(mm, ss);
        }
    }
}

// ---------------------------------------------------------------------------
// Reduce: one wave per sample; 128 slice-partials -> butterfly -> out.
// ---------------------------------------------------------------------------
__global__ __launch_bounds__(64) void kde_reduce(
    const float2* __restrict__ part, float* __restrict__ out)
{
    int b = blockIdx.x, t = threadIdx.x;
    float2 v0 = part[(size_t)t * BB + b];
    float2 v1 = part[(size_t)(t + 64) * BB + b];
    float mm = fmaxf(v0.x, v1.x);
    float ss = v0.y * EXP2(v0.x - mm) + v1.y * EXP2(v1.x - mm);
    #pragma unroll
    for (int off = 32; off; off >>= 1) {
        float mo = __shfl_xor(mm, off, 64);
        float so = __shfl_xor(ss, off, 64);
        float mn = fmaxf(mm, mo);
        ss = ss * EXP2(mm - mn) + so * EXP2(mo - mn);
        mm = mn;
    }
    if (t == 0) out[b] = (mm + __log2f(ss)) * LN2;
}

extern "C" void kernel_launch(void* const* d_in, const int* in_sizes, int n_in,
                              void* d_out, int out_size, void* d_ws, size_t ws_size,
                              hipStream_t stream) {
    const float* x  = (const float*)d_in[0];
    const float* mu = (const float*)d_in[1];
    const float* st = (const float*)d_in[2];
    const float* w  = (const float*)d_in[3];
    float* out = (float*)d_out;

    char* ws = (char*)d_ws;
    ushort* Ah = (ushort*)(ws);                       // 16384*32*2 = 1 MB
    ushort* Al = (ushort*)(ws + (1u << 20));          // 1 MB
    ushort* Xh = (ushort*)(ws + (2u << 20));          // 2048*32*2 = 128 KB
    ushort* Xl = (ushort*)(ws + (2u << 20) + (128u << 10));
    float2* part = (float2*)(ws + (4u << 20));        // 128*2048*8 = 2 MB

    hipLaunchKernelGGL(kde_prep, dim3(64 + 8), dim3(256), 0, stream,
                       x, mu, st, w, Ah, Al, Xh, Xl);
    hipLaunchKernelGGL(kde_main, dim3(NBG * NSLICES / 4), dim3(256), 0, stream,
                       Ah, Al, Xh, Xl, part);
    hipLaunchKernelGGL(kde_reduce, dim3(BB), dim3(64), 0, stream,
                       part, out);
}